// Round 7
// baseline (134.356 us; speedup 1.0000x reference)
//
#include <hip/hip_runtime.h>

typedef __bf16 bf16_t;
typedef __bf16 bf16x8 __attribute__((ext_vector_type(8)));
typedef __bf16 bf16x4 __attribute__((ext_vector_type(4)));
typedef float f32x4 __attribute__((ext_vector_type(4)));
typedef float f32x16 __attribute__((ext_vector_type(16)));

static constexpr int kC = 256;   // channels
static constexpr int kN = 1024;  // tokens (32x32)
static constexpr int kB = 32;    // batch

__device__ __forceinline__ void gload_lds16(const bf16_t* g, bf16_t* l) {
  __builtin_amdgcn_global_load_lds(
      (const __attribute__((address_space(1))) unsigned int*)g,
      (__attribute__((address_space(3))) unsigned int*)l, 16, 0, 0);
}

__device__ __forceinline__ unsigned cvt_pk_bf16(float a, float b) {
  unsigned r;
  asm("v_cvt_pk_bf16_f32 %0, %1, %2" : "=v"(r) : "v"(a), "v"(b));
  return r;
}

// exchange: a's high 32 lanes <-> b's low 32 lanes (both regs updated)
__device__ __forceinline__ void pl32swap(unsigned& a, unsigned& b) {
  asm("v_permlane32_swap_b32 %0, %1" : "+v"(a), "+v"(b));
}

__device__ __forceinline__ float cross_half_sum(float rs) {
  unsigned a = __builtin_bit_cast(unsigned, rs), b = a;
  pl32swap(a, b);
  return __builtin_bit_cast(float, a) + __builtin_bit_cast(float, b);
}

// ------- fused GroupNorm: one block per (b,g); stats + normalize in one x read -------
__global__ __launch_bounds__(256) void gn_fused_k(const float* __restrict__ x,
                                                  const float* __restrict__ gamma,
                                                  const float* __restrict__ beta,
                                                  bf16_t* __restrict__ hn) {
  __shared__ float xs[8 * 1040];  // [c_local][n] pad 1040
  __shared__ float red[8];
  __shared__ float stat[2];
  int bg = blockIdx.x;
  int b = bg >> 5, g = bg & 31;
  int t = threadIdx.x;
  const float* base = x + (size_t)bg * 8192;
  float s = 0.f, q = 0.f;
#pragma unroll
  for (int i = 0; i < 8; ++i) {
    float4 v = *(const float4*)(base + i * 1024 + t * 4);
    *(float4*)(xs + i * 1040 + t * 4) = v;
    s += v.x + v.y + v.z + v.w;
    q += v.x * v.x + v.y * v.y + v.z * v.z + v.w * v.w;
  }
#pragma unroll
  for (int o = 32; o; o >>= 1) { s += __shfl_down(s, o); q += __shfl_down(q, o); }
  int w = t >> 6;
  if ((t & 63) == 0) { red[w] = s; red[4 + w] = q; }
  __syncthreads();
  if (t == 0) {
    float S = red[0] + red[1] + red[2] + red[3];
    float Q = red[4] + red[5] + red[6] + red[7];
    float mean = S * (1.f / 8192.f);
    float var = Q * (1.f / 8192.f) - mean * mean;  // biased var matches jnp.var
    stat[0] = mean;
    stat[1] = rsqrtf(var + 1e-5f);
  }
  __syncthreads();
  float mean = stat[0], rstd = stat[1];
  float gmb[8], btb[8];
#pragma unroll
  for (int j = 0; j < 8; ++j) { gmb[j] = gamma[g * 8 + j]; btb[j] = beta[g * 8 + j]; }
  bf16_t* hb = hn + (size_t)b * (kN * kC) + g * 8;
#pragma unroll
  for (int i = 0; i < 4; ++i) {
    int n = i * 256 + t;
    bf16x8 o;
#pragma unroll
    for (int j = 0; j < 8; ++j)
      o[j] = (bf16_t)((xs[j * 1040 + n] - mean) * rstd * gmb[j] + btb[j]);
    *(bf16x8*)(hb + (size_t)n * kC) = o;
  }
}

// ---------------- cast the four 256x256 f32 weights to bf16 ----------------
__global__ __launch_bounds__(256) void castw_k(const float* __restrict__ wq,
                                               const float* __restrict__ wk,
                                               const float* __restrict__ wv,
                                               const float* __restrict__ wh,
                                               bf16_t* __restrict__ o) {
  int i = blockIdx.x * 256 + threadIdx.x;
  o[i] = (bf16_t)wq[i];
  o[i + 65536] = (bf16_t)wk[i];
  o[i + 131072] = (bf16_t)wv[i];
  o[i + 196608] = (bf16_t)wh[i];
}

// ---- fused flash attention v3: 512 blocks x 4 waves (2 qg x 2 h), KVBLK=32 ----
// 2 independent blocks/CU (64KB LDS) -> cross-block phase overlap. Fixed-m softmax
// (Q pre-scaled by log2e/16 so P = exp2(S)); redundant QK per h-pair (no exchange);
// PV split by channel half. All cross-half moves via v_permlane32_swap (no LDS).
// QT, KT: [B][N][C] bf16 (Q pre-scaled). VV: [B][C][N]. OT: [B][N][C] bf16.
__global__ __launch_bounds__(256, 2) void fattn_k(const bf16_t* __restrict__ QT,
                                                  const bf16_t* __restrict__ KT,
                                                  const bf16_t* __restrict__ VV,
                                                  bf16_t* __restrict__ OT) {
  __shared__ char smem[65536];  // K[2][32*256] 32K | V[2][256*32] 32K
  bf16_t* lK = (bf16_t*)smem;
  bf16_t* lV = (bf16_t*)(smem + 32768);
  int t = threadIdx.x;
  int wid = t >> 6, lane = t & 63;
  int l31 = lane & 31, hi = lane >> 5;
  int qg = wid & 1, h = wid >> 1;
  int ts = t & 127;
  int bid = blockIdx.x;
  int b = ((bid & 7) << 2) | ((bid >> 3) & 3);  // XCD swizzle (b from low 5 bits)
  int qt = bid >> 5;                            // 0..15
  const bf16_t* Qb = QT + (size_t)b * (kN * kC);
  const bf16_t* Kb = KT + (size_t)b * (kN * kC);
  const bf16_t* Vb = VV + (size_t)b * (kC * kN);
  int q0 = qt * 64 + qg * 32;

  // hoist Q (B-operand): qf[ks] = Qs[q0 + l31][ks*16 + hi*8 .. +7]
  bf16x8 qf[16];
#pragma unroll
  for (int ks = 0; ks < 16; ++ks)
    qf[ks] = *(const bf16x8*)(Qb + (size_t)(q0 + l31) * kC + ks * 16 + hi * 8);

  f32x16 acc[4] = {};  // own c-half: col = h*128+ct*32+l31; row q = (r&3)+8*(r>>2)+4*hi
  float lsum = 0.f;

  auto STAGE = [&](int buf, int k0) {
    if (wid < 2) {  // K tile [32][256]: 1024 16B chunks, LDS slot s holds chunk s^row
#pragma unroll
      for (int i = 0; i < 8; ++i) {
        int ck = i * 128 + ts;
        int row = ck >> 5, s = ck & 31;
        gload_lds16(Kb + (size_t)(k0 + row) * kC + ((s ^ row) << 3),
                    lK + buf * 8192 + ck * 8);
      }
    } else {  // V tile [256][32]: 1024 16B chunks (4/row), slot s holds chunk s^((c>>1)&3)
#pragma unroll
      for (int i = 0; i < 8; ++i) {
        int cv = i * 128 + ts;
        int c = cv >> 2, s = cv & 3;
        gload_lds16(Vb + (size_t)c * kN + k0 + ((s ^ ((c >> 1) & 3)) << 3),
                    lV + buf * 8192 + cv * 8);
      }
    }
  };

  auto COMPUTE = [&](int buf) {
    const bf16_t* bK = lK + buf * 8192;
    const bf16_t* bV = lV + buf * 8192;
    // S^T = K . Q^T over this 32-kv tile (one chain; cross-block waves fill latency)
    f32x16 s0 = {};
    __builtin_amdgcn_s_setprio(1);
#pragma unroll
    for (int ks = 0; ks < 16; ++ks) {
      int ch = 2 * ks + hi;
      bf16x8 kf = *(const bf16x8*)(bK + l31 * 256 + ((ch ^ l31) << 3));
      s0 = __builtin_amdgcn_mfma_f32_32x32x16_bf16(kf, qf[ks], s0, 0, 0, 0);
    }
    __builtin_amdgcn_s_setprio(0);
    // fixed-m exp (Q pre-scaled: P = exp2(S))
    float rs = 0.f;
#pragma unroll
    for (int r = 0; r < 16; ++r) {
      float p = exp2f(s0[r]);
      s0[r] = p;
      rs += p;
    }
    lsum += cross_half_sum(rs);  // full 32-kv row sum for q = l31
    // P -> A-frags via cvt_pk + permlane32_swap (no LDS, no selects)
    unsigned A0 = cvt_pk_bf16(s0[0], s0[1]), A1 = cvt_pk_bf16(s0[2], s0[3]);
    unsigned B0 = cvt_pk_bf16(s0[4], s0[5]), B1 = cvt_pk_bf16(s0[6], s0[7]);
    unsigned C0 = cvt_pk_bf16(s0[8], s0[9]), C1 = cvt_pk_bf16(s0[10], s0[11]);
    unsigned D0 = cvt_pk_bf16(s0[12], s0[13]), D1 = cvt_pk_bf16(s0[14], s0[15]);
    pl32swap(A0, B0);  // A0 -> pw[0][0], B0 -> pw[0][2]
    pl32swap(A1, B1);
    pl32swap(C0, D0);
    pl32swap(C1, D1);
    uint4 u0 = make_uint4(A0, A1, B0, B1);  // k-slot gs=0 (kv 0..15)
    uint4 u1 = make_uint4(C0, C1, D0, D1);  // k-slot gs=1 (kv 16..31)
    bf16x8 pa0 = __builtin_bit_cast(bf16x8, u0);
    bf16x8 pa1 = __builtin_bit_cast(bf16x8, u1);
    // PV: own 128-channel half
    __builtin_amdgcn_s_setprio(1);
#pragma unroll
    for (int gs = 0; gs < 2; ++gs) {
      bf16x8 paf = gs ? pa1 : pa0;
#pragma unroll
      for (int ct = 0; ct < 4; ++ct) {
        int c = h * 128 + ct * 32 + l31;
        int ch = gs * 2 + hi;
        bf16x8 vf = *(const bf16x8*)(bV + c * 32 + ((ch ^ ((c >> 1) & 3)) << 3));
        acc[ct] = __builtin_amdgcn_mfma_f32_32x32x16_bf16(paf, vf, acc[ct], 0, 0, 0);
      }
    }
    __builtin_amdgcn_s_setprio(0);
  };

  STAGE(0, 0);
  for (int kt = 0; kt < 32; ++kt) {
    if (kt < 31) {
      STAGE((kt + 1) & 1, (kt + 1) * 32);               // prefetch next tile
      asm volatile("s_waitcnt vmcnt(8)" ::: "memory");  // tile-kt loads landed
    } else {
      asm volatile("s_waitcnt vmcnt(0)" ::: "memory");
    }
    __builtin_amdgcn_s_barrier();  // tile kt staged for all waves
    COMPUTE(kt & 1);
    __builtin_amdgcn_s_barrier();  // reads done before next-iter restage
  }

  // epilogue: full lsum per q-row (redundant across h); store own c-half
  float inv = 1.f / lsum;
  float invR[16];
#pragma unroll
  for (int r = 0; r < 16; ++r)
    invR[r] = __shfl(inv, (r & 3) + 8 * (r >> 2) + 4 * hi);
  bf16_t* Ob = OT + (size_t)b * (kN * kC);
#pragma unroll
  for (int ct = 0; ct < 4; ++ct)
#pragma unroll
    for (int r = 0; r < 16; ++r) {
      int qr = (r & 3) + 8 * (r >> 2) + 4 * hi;
      Ob[(size_t)(q0 + qr) * kC + h * 128 + ct * 32 + l31] =
          (bf16_t)(acc[ct][r] * invR[r]);
    }
}

// ---------------- merged QKV GEMM: W stacked [768][256], HN [B][N][C] ----------------
// tmi 0-1 -> Q_t (transposed store, (acc+bq)*log2e/16); 2-3 -> K_t (bk); 4-5 -> V [c][n]
__global__ __launch_bounds__(256) void qkv_gemm_k(const bf16_t* __restrict__ W,
                                                  const bf16_t* __restrict__ HNall,
                                                  bf16_t* __restrict__ QTo,
                                                  bf16_t* __restrict__ KTo,
                                                  bf16_t* __restrict__ VVo,
                                                  const float* __restrict__ bq,
                                                  const float* __restrict__ bk,
                                                  const float* __restrict__ bv) {
  __shared__ bf16_t lA[128 * 64];
  __shared__ bf16_t lB[128 * 64];
  int bid = blockIdx.x;
  int b = bid / 48;
  int rem = bid - b * 48;
  int tmi = rem >> 3, tni = rem & 7;
  const bf16_t* Ab = W + (size_t)tmi * 128 * 256;
  const bf16_t* Bb = HNall + (size_t)b * (kN * kC) + (size_t)tni * 128 * 256;
  int t = threadIdx.x;
  int wid = t >> 6, l = t & 63;
  int wm = wid >> 1, wn = wid & 1;
  int lr = l & 15, lk = l >> 4;
  f32x4 acc[4][4] = {};
  for (int k0 = 0; k0 < 256; k0 += 64) {
    __syncthreads();
    // global_load_lds staging: linear LDS dest, inverse-swizzled global source
#pragma unroll
    for (int i = 0; i < 4; ++i) {
      int ci = i * 256 + t;
      int row = ci >> 3, s = ci & 7;
      gload_lds16(Ab + (size_t)row * 256 + k0 + ((s ^ (row & 7)) << 3), lA + ci * 8);
      gload_lds16(Bb + (size_t)row * 256 + k0 + ((s ^ (row & 7)) << 3), lB + ci * 8);
    }
    __syncthreads();  // compiler drains vmcnt before barrier
#pragma unroll
    for (int kk = 0; kk < 2; ++kk) {
      bf16x8 af[4], bfr[4];
#pragma unroll
      for (int mf = 0; mf < 4; ++mf) {
        int r = wm * 64 + mf * 16 + lr;
        int ch = kk * 4 + lk;
        af[mf] = *(const bf16x8*)(lA + r * 64 + ((ch ^ (r & 7)) * 8));
      }
#pragma unroll
      for (int nf = 0; nf < 4; ++nf) {
        int r = wn * 64 + nf * 16 + lr;
        int ch = kk * 4 + lk;
        bfr[nf] = *(const bf16x8*)(lB + r * 64 + ((ch ^ (r & 7)) * 8));
      }
#pragma unroll
      for (int mf = 0; mf < 4; ++mf)
#pragma unroll
        for (int nf = 0; nf < 4; ++nf)
          acc[mf][nf] = __builtin_amdgcn_mfma_f32_16x16x32_bf16(af[mf], bfr[nf],
                                                                acc[mf][nf], 0, 0, 0);
    }
  }
  int seg = tmi >> 1;
  int rb = (tmi & 1) * 128 + wm * 64;
  int cb = tni * 128 + wn * 64;
  if (seg < 2) {  // Q_t / K_t: transposed bf16 store + bias[r] (+ scale for Q)
    bf16_t* D = (seg ? KTo : QTo) + (size_t)b * (kN * kC);
    const float* bias = seg ? bk : bq;
    float sc = seg ? 1.f : 0.09016844f;  // log2(e)/16 folded into Q
#pragma unroll
    for (int mf = 0; mf < 4; ++mf)
#pragma unroll
      for (int nf = 0; nf < 4; ++nf) {
        int r0 = rb + mf * 16 + lk * 4;
        int c = cb + nf * 16 + lr;
        bf16x4 v;
#pragma unroll
        for (int i = 0; i < 4; ++i) v[i] = (bf16_t)((acc[mf][nf][i] + bias[r0 + i]) * sc);
        *(bf16x4*)(D + (size_t)c * kC + r0) = v;
      }
  } else {  // V: natural bf16 store [c][n] + bias[r]
    bf16_t* D = VVo + (size_t)b * (kC * kN);
#pragma unroll
    for (int mf = 0; mf < 4; ++mf)
#pragma unroll
      for (int nf = 0; nf < 4; ++nf) {
        int r0 = rb + mf * 16 + lk * 4;
        int c = cb + nf * 16 + lr;
#pragma unroll
        for (int i = 0; i < 4; ++i)
          D[(size_t)(r0 + i) * kN + c] = (bf16_t)(acc[mf][nf][i] + bv[r0 + i]);
      }
  }
}

// ---------------- out-proj GEMM: transposed f32 store + resid + bias[c] ----------------
__global__ __launch_bounds__(256) void out_gemm_k(const bf16_t* __restrict__ A,  // O_t
                                                  const bf16_t* __restrict__ BT, // Wh
                                                  float* __restrict__ Dst,
                                                  const float* __restrict__ bias,
                                                  const float* __restrict__ resid) {
  __shared__ bf16_t lA[128 * 64];
  __shared__ bf16_t lB[128 * 64];
  int bid = blockIdx.x;
  int b = bid >> 4;
  int rem = bid & 15;
  int tmi = rem >> 1, tni = rem & 1;
  const bf16_t* Ab = A + (size_t)b * (kN * kC) + (size_t)tmi * 128 * 256;
  const bf16_t* Bb = BT + (size_t)tni * 128 * 256;
  int t = threadIdx.x;
  int wid = t >> 6, l = t & 63;
  int wm = wid >> 1, wn = wid & 1;
  int lr = l & 15, lk = l >> 4;
  f32x4 acc[4][4] = {};
  for (int k0 = 0; k0 < 256; k0 += 64) {
    __syncthreads();
#pragma unroll
    for (int i = 0; i < 4; ++i) {
      int ci = i * 256 + t;
      int row = ci >> 3, s = ci & 7;
      gload_lds16(Ab + (size_t)row * 256 + k0 + ((s ^ (row & 7)) << 3), lA + ci * 8);
      gload_lds16(Bb + (size_t)row * 256 + k0 + ((s ^ (row & 7)) << 3), lB + ci * 8);
    }
    __syncthreads();
#pragma unroll
    for (int kk = 0; kk < 2; ++kk) {
      bf16x8 af[4], bfr[4];
#pragma unroll
      for (int mf = 0; mf < 4; ++mf) {
        int r = wm * 64 + mf * 16 + lr;
        int ch = kk * 4 + lk;
        af[mf] = *(const bf16x8*)(lA + r * 64 + ((ch ^ (r & 7)) * 8));
      }
#pragma unroll
      for (int nf = 0; nf < 4; ++nf) {
        int r = wn * 64 + nf * 16 + lr;
        int ch = kk * 4 + lk;
        bfr[nf] = *(const bf16x8*)(lB + r * 64 + ((ch ^ (r & 7)) * 8));
      }
#pragma unroll
      for (int mf = 0; mf < 4; ++mf)
#pragma unroll
        for (int nf = 0; nf < 4; ++nf)
          acc[mf][nf] = __builtin_amdgcn_mfma_f32_16x16x32_bf16(af[mf], bfr[nf],
                                                                acc[mf][nf], 0, 0, 0);
    }
  }
  int rb = tmi * 128 + wm * 64;
  int cb = tni * 128 + wn * 64;
  float* D = Dst + (size_t)b * (kC * kN);
  const float* R = resid + (size_t)b * (kC * kN);
#pragma unroll
  for (int mf = 0; mf < 4; ++mf)
#pragma unroll
    for (int nf = 0; nf < 4; ++nf) {
      int r0 = rb + mf * 16 + lk * 4;  // token n
      int c = cb + nf * 16 + lr;       // channel co
      float4 rv = *(const float4*)(R + (size_t)c * kN + r0);
      float bc = bias[c];
      float4 o2 = make_float4(acc[mf][nf][0] + rv.x + bc, acc[mf][nf][1] + rv.y + bc,
                              acc[mf][nf][2] + rv.z + bc, acc[mf][nf][3] + rv.w + bc);
      *(float4*)(D + (size_t)c * kN + r0) = o2;
    }
}

extern "C" void kernel_launch(void* const* d_in, const int* in_sizes, int n_in,
                              void* d_out, int out_size, void* d_ws, size_t ws_size,
                              hipStream_t stream) {
  (void)in_sizes; (void)n_in; (void)out_size; (void)ws_size;
  const float* x = (const float*)d_in[0];
  const float* gamma = (const float*)d_in[1];
  const float* beta = (const float*)d_in[2];
  const float* wq = (const float*)d_in[3];
  const float* bq = (const float*)d_in[4];
  const float* wk = (const float*)d_in[5];
  const float* bk = (const float*)d_in[6];
  const float* wv = (const float*)d_in[7];
  const float* bv = (const float*)d_in[8];
  const float* wh = (const float*)d_in[9];
  const float* bh = (const float*)d_in[10];
  float* out = (float*)d_out;

  char* ws = (char*)d_ws;
  bf16_t* HN = (bf16_t*)(ws);                // Hn_t [B][N][C]; reused as O_t after fattn
  bf16_t* QT = (bf16_t*)(ws + 16777216);     // Q_t [B][N][C] (pre-scaled)
  bf16_t* KT = (bf16_t*)(ws + 33554432);     // K_t [B][N][C]
  bf16_t* VV = (bf16_t*)(ws + 50331648);     // V   [B][C][N]
  bf16_t* WB = (bf16_t*)(ws + 67108864);     // Wq|Wk|Wv|Wh bf16 (stacked)

  gn_fused_k<<<kB * 32, 256, 0, stream>>>(x, gamma, beta, HN);
  castw_k<<<256, 256, 0, stream>>>(wq, wk, wv, wh, WB);
  // Q_t, K_t, V in one dispatch (stacked 768x256 weight)
  qkv_gemm_k<<<kB * 48, 256, 0, stream>>>(WB, HN, QT, KT, VV, bq, bk, bv);
  // fused attention -> O_t in HN
  fattn_k<<<512, 256, 0, stream>>>(QT, KT, VV, HN);
  // out[co][n] = x + (O_t . Wh^T)^T + bh
  out_gemm_k<<<kB * 16, 256, 0, stream>>>(HN, WB + 196608, out, bh, x);
}

// Round 8
// 131.630 us; speedup vs baseline: 1.0207x; 1.0207x over previous
//
#include <hip/hip_runtime.h>

typedef __bf16 bf16_t;
typedef __bf16 bf16x8 __attribute__((ext_vector_type(8)));
typedef __bf16 bf16x4 __attribute__((ext_vector_type(4)));
typedef float f32x4 __attribute__((ext_vector_type(4)));
typedef float f32x16 __attribute__((ext_vector_type(16)));

static constexpr int kC = 256;   // channels
static constexpr int kN = 1024;  // tokens (32x32)
static constexpr int kB = 32;    // batch

__device__ __forceinline__ void gload_lds16(const bf16_t* g, bf16_t* l) {
  __builtin_amdgcn_global_load_lds(
      (const __attribute__((address_space(1))) unsigned int*)g,
      (__attribute__((address_space(3))) unsigned int*)l, 16, 0, 0);
}

__device__ __forceinline__ unsigned cvt_pk_bf16(float a, float b) {
  unsigned r;
  asm("v_cvt_pk_bf16_f32 %0, %1, %2" : "=v"(r) : "v"(a), "v"(b));
  return r;
}

// exchange: a's high 32 lanes <-> b's low 32 lanes (both regs updated)
__device__ __forceinline__ void pl32swap(unsigned& a, unsigned& b) {
  asm("v_permlane32_swap_b32 %0, %1" : "+v"(a), "+v"(b));
}

__device__ __forceinline__ float cross_half_sum(float rs) {
  unsigned a = __builtin_bit_cast(unsigned, rs), b = a;
  pl32swap(a, b);
  return __builtin_bit_cast(float, a) + __builtin_bit_cast(float, b);
}

// ------- fused GroupNorm (+ weight cast blocks): grid = 1024 gn + 256 castw -------
__global__ __launch_bounds__(256) void gn_castw_k(const float* __restrict__ x,
                                                  const float* __restrict__ gamma,
                                                  const float* __restrict__ beta,
                                                  bf16_t* __restrict__ hn,
                                                  const float* __restrict__ wq,
                                                  const float* __restrict__ wk,
                                                  const float* __restrict__ wv,
                                                  const float* __restrict__ wh,
                                                  bf16_t* __restrict__ wb) {
  __shared__ float xs[8 * 1040];  // [c_local][n] pad 1040
  __shared__ float red[8];
  __shared__ float stat[2];
  int t = threadIdx.x;
  if (blockIdx.x >= 1024) {  // weight cast: 256 blocks x 256 thr
    int i = (blockIdx.x - 1024) * 256 + t;
    wb[i] = (bf16_t)wq[i];
    wb[i + 65536] = (bf16_t)wk[i];
    wb[i + 131072] = (bf16_t)wv[i];
    wb[i + 196608] = (bf16_t)wh[i];
    return;
  }
  int bg = blockIdx.x;
  int b = bg >> 5, g = bg & 31;
  const float* base = x + (size_t)bg * 8192;
  float s = 0.f, q = 0.f;
#pragma unroll
  for (int i = 0; i < 8; ++i) {
    float4 v = *(const float4*)(base + i * 1024 + t * 4);
    *(float4*)(xs + i * 1040 + t * 4) = v;
    s += v.x + v.y + v.z + v.w;
    q += v.x * v.x + v.y * v.y + v.z * v.z + v.w * v.w;
  }
#pragma unroll
  for (int o = 32; o; o >>= 1) { s += __shfl_down(s, o); q += __shfl_down(q, o); }
  int w = t >> 6;
  if ((t & 63) == 0) { red[w] = s; red[4 + w] = q; }
  __syncthreads();
  if (t == 0) {
    float S = red[0] + red[1] + red[2] + red[3];
    float Q = red[4] + red[5] + red[6] + red[7];
    float mean = S * (1.f / 8192.f);
    float var = Q * (1.f / 8192.f) - mean * mean;  // biased var matches jnp.var
    stat[0] = mean;
    stat[1] = rsqrtf(var + 1e-5f);
  }
  __syncthreads();
  float mean = stat[0], rstd = stat[1];
  float gmb[8], btb[8];
#pragma unroll
  for (int j = 0; j < 8; ++j) { gmb[j] = gamma[g * 8 + j]; btb[j] = beta[g * 8 + j]; }
  bf16_t* hb = hn + (size_t)b * (kN * kC) + g * 8;
#pragma unroll
  for (int i = 0; i < 4; ++i) {
    int n = i * 256 + t;
    bf16x8 o;
#pragma unroll
    for (int j = 0; j < 8; ++j)
      o[j] = (bf16_t)((xs[j * 1040 + n] - mean) * rstd * gmb[j] + btb[j]);
    *(bf16x8*)(hb + (size_t)n * kC) = o;
  }
}

// ---- fused flash attention v4: pipelined compute (split QK chains, PV/exp overlap) ----
// 512 blocks x 4 waves (2 qg x 2 h), KVBLK=32, 2 blocks/CU. Fixed-m softmax
// (Q pre-scaled by log2e/16 -> P = exp2(S)); redundant QK per h-pair; PV c-half split.
// QT, KT: [B][N][C] bf16 (Q pre-scaled). VV: [B][C][N]. OT: [B][N][C] bf16.
__global__ __launch_bounds__(256, 2) void fattn_k(const bf16_t* __restrict__ QT,
                                                  const bf16_t* __restrict__ KT,
                                                  const bf16_t* __restrict__ VV,
                                                  bf16_t* __restrict__ OT) {
  __shared__ char smem[65536];  // K[2][32*256] 32K | V[2][256*32] 32K
  bf16_t* lK = (bf16_t*)smem;
  bf16_t* lV = (bf16_t*)(smem + 32768);
  int t = threadIdx.x;
  int wid = t >> 6, lane = t & 63;
  int l31 = lane & 31, hi = lane >> 5;
  int qg = wid & 1, h = wid >> 1;
  int ts = t & 127;
  int bid = blockIdx.x;
  int b = ((bid & 7) << 2) | ((bid >> 3) & 3);  // XCD swizzle (b from low 5 bits)
  int qt = bid >> 5;                            // 0..15
  const bf16_t* Qb = QT + (size_t)b * (kN * kC);
  const bf16_t* Kb = KT + (size_t)b * (kN * kC);
  const bf16_t* Vb = VV + (size_t)b * (kC * kN);
  int q0 = qt * 64 + qg * 32;

  // hoist Q (B-operand): qf[ks] = Qs[q0 + l31][ks*16 + hi*8 .. +7]
  bf16x8 qf[16];
#pragma unroll
  for (int ks = 0; ks < 16; ++ks)
    qf[ks] = *(const bf16x8*)(Qb + (size_t)(q0 + l31) * kC + ks * 16 + hi * 8);

  f32x16 acc[4] = {};  // own c-half: col = h*128+ct*32+l31; row q = (r&3)+8*(r>>2)+4*hi
  float lsum = 0.f;

  auto STAGE = [&](int buf, int k0) {
    if (wid < 2) {  // K tile [32][256]: 1024 16B chunks, LDS slot s holds chunk s^row
#pragma unroll
      for (int i = 0; i < 8; ++i) {
        int ck = i * 128 + ts;
        int row = ck >> 5, s = ck & 31;
        gload_lds16(Kb + (size_t)(k0 + row) * kC + ((s ^ row) << 3),
                    lK + buf * 8192 + ck * 8);
      }
    } else {  // V tile [256][32]: 1024 16B chunks (4/row), slot s holds chunk s^((c>>1)&3)
#pragma unroll
      for (int i = 0; i < 8; ++i) {
        int cv = i * 128 + ts;
        int c = cv >> 2, s = cv & 3;
        gload_lds16(Vb + (size_t)c * kN + k0 + ((s ^ ((c >> 1) & 3)) << 3),
                    lV + buf * 8192 + cv * 8);
      }
    }
  };

  auto COMPUTE = [&](int buf) {
    const bf16_t* bK = lK + buf * 8192;
    const bf16_t* bV = lV + buf * 8192;
    // S^T = K . Q^T : two independent 8-deep chains (halve exposed MFMA latency)
    f32x16 sa = {}, sb = {};
    __builtin_amdgcn_s_setprio(1);
#pragma unroll
    for (int ks = 0; ks < 8; ++ks) {
      bf16x8 kf0 = *(const bf16x8*)(bK + l31 * 256 + (((2 * ks + hi) ^ l31) << 3));
      sa = __builtin_amdgcn_mfma_f32_32x32x16_bf16(kf0, qf[ks], sa, 0, 0, 0);
      bf16x8 kf1 = *(const bf16x8*)(bK + l31 * 256 + (((2 * ks + 16 + hi) ^ l31) << 3));
      sb = __builtin_amdgcn_mfma_f32_32x32x16_bf16(kf1, qf[ks + 8], sb, 0, 0, 0);
    }
    __builtin_amdgcn_s_setprio(0);
    // lower P half (rows 0..7) -> pa0 -> PV gs=0 issues while upper half's exp runs
    float rs = 0.f;
    float e0, e1, e2, e3, e4, e5, e6, e7;
    e0 = exp2f(sa[0] + sb[0]); e1 = exp2f(sa[1] + sb[1]);
    e2 = exp2f(sa[2] + sb[2]); e3 = exp2f(sa[3] + sb[3]);
    e4 = exp2f(sa[4] + sb[4]); e5 = exp2f(sa[5] + sb[5]);
    e6 = exp2f(sa[6] + sb[6]); e7 = exp2f(sa[7] + sb[7]);
    rs += e0 + e1 + e2 + e3 + e4 + e5 + e6 + e7;
    unsigned A0 = cvt_pk_bf16(e0, e1), A1 = cvt_pk_bf16(e2, e3);
    unsigned B0 = cvt_pk_bf16(e4, e5), B1 = cvt_pk_bf16(e6, e7);
    pl32swap(A0, B0);
    pl32swap(A1, B1);
    uint4 u0 = make_uint4(A0, A1, B0, B1);
    bf16x8 pa0 = __builtin_bit_cast(bf16x8, u0);
    __builtin_amdgcn_s_setprio(1);
#pragma unroll
    for (int ct = 0; ct < 4; ++ct) {
      int c = h * 128 + ct * 32 + l31;
      bf16x8 vf = *(const bf16x8*)(bV + c * 32 + ((hi ^ ((c >> 1) & 3)) << 3));
      acc[ct] = __builtin_amdgcn_mfma_f32_32x32x16_bf16(pa0, vf, acc[ct], 0, 0, 0);
    }
    __builtin_amdgcn_s_setprio(0);
    // upper P half (rows 8..15): VALU overlaps the in-flight gs0 MFMAs
    e0 = exp2f(sa[8] + sb[8]);   e1 = exp2f(sa[9] + sb[9]);
    e2 = exp2f(sa[10] + sb[10]); e3 = exp2f(sa[11] + sb[11]);
    e4 = exp2f(sa[12] + sb[12]); e5 = exp2f(sa[13] + sb[13]);
    e6 = exp2f(sa[14] + sb[14]); e7 = exp2f(sa[15] + sb[15]);
    rs += e0 + e1 + e2 + e3 + e4 + e5 + e6 + e7;
    unsigned C0 = cvt_pk_bf16(e0, e1), C1 = cvt_pk_bf16(e2, e3);
    unsigned D0 = cvt_pk_bf16(e4, e5), D1 = cvt_pk_bf16(e6, e7);
    pl32swap(C0, D0);
    pl32swap(C1, D1);
    uint4 u1 = make_uint4(C0, C1, D0, D1);
    bf16x8 pa1 = __builtin_bit_cast(bf16x8, u1);
    __builtin_amdgcn_s_setprio(1);
#pragma unroll
    for (int ct = 0; ct < 4; ++ct) {
      int c = h * 128 + ct * 32 + l31;
      bf16x8 vf = *(const bf16x8*)(bV + c * 32 + (((2 + hi) ^ ((c >> 1) & 3)) << 3));
      acc[ct] = __builtin_amdgcn_mfma_f32_32x32x16_bf16(pa1, vf, acc[ct], 0, 0, 0);
    }
    __builtin_amdgcn_s_setprio(0);
    lsum += cross_half_sum(rs);  // full 32-kv row sum for q = l31
  };

  STAGE(0, 0);
  for (int kt = 0; kt < 32; ++kt) {
    if (kt < 31) {
      STAGE((kt + 1) & 1, (kt + 1) * 32);               // prefetch next tile
      asm volatile("s_waitcnt vmcnt(8)" ::: "memory");  // tile-kt loads landed
    } else {
      asm volatile("s_waitcnt vmcnt(0)" ::: "memory");
    }
    __builtin_amdgcn_s_barrier();  // tile kt staged for all waves
    COMPUTE(kt & 1);
    __builtin_amdgcn_s_barrier();  // reads done before next-iter restage
  }

  // epilogue: full lsum per q-row (redundant across h); store own c-half
  float inv = 1.f / lsum;
  float invR[16];
#pragma unroll
  for (int r = 0; r < 16; ++r)
    invR[r] = __shfl(inv, (r & 3) + 8 * (r >> 2) + 4 * hi);
  bf16_t* Ob = OT + (size_t)b * (kN * kC);
#pragma unroll
  for (int ct = 0; ct < 4; ++ct)
#pragma unroll
    for (int r = 0; r < 16; ++r) {
      int qr = (r & 3) + 8 * (r >> 2) + 4 * hi;
      Ob[(size_t)(q0 + qr) * kC + h * 128 + ct * 32 + l31] =
          (bf16_t)(acc[ct][r] * invR[r]);
    }
}

// ---------------- merged QKV GEMM, double-buffered stage-ahead (T3-min) ----------------
// W stacked [768][256]; tmi 0-1 -> Q_t (scaled), 2-3 -> K_t, 4-5 -> V [c][n]
__global__ __launch_bounds__(256) void qkv_gemm_k(const bf16_t* __restrict__ W,
                                                  const bf16_t* __restrict__ HNall,
                                                  bf16_t* __restrict__ QTo,
                                                  bf16_t* __restrict__ KTo,
                                                  bf16_t* __restrict__ VVo,
                                                  const float* __restrict__ bq,
                                                  const float* __restrict__ bk,
                                                  const float* __restrict__ bv) {
  __shared__ bf16_t lA[2][128 * 64];
  __shared__ bf16_t lB[2][128 * 64];
  int bid = blockIdx.x;
  int b = bid / 48;
  int rem = bid - b * 48;
  int tmi = rem >> 3, tni = rem & 7;
  const bf16_t* Ab = W + (size_t)tmi * 128 * 256;
  const bf16_t* Bb = HNall + (size_t)b * (kN * kC) + (size_t)tni * 128 * 256;
  int t = threadIdx.x;
  int wid = t >> 6, l = t & 63;
  int wm = wid >> 1, wn = wid & 1;
  int lr = l & 15, lk = l >> 4;
  f32x4 acc[4][4] = {};
  auto STAGE = [&](int buf, int k0) {
#pragma unroll
    for (int i = 0; i < 4; ++i) {
      int ci = i * 256 + t;
      int row = ci >> 3, s = ci & 7;
      gload_lds16(Ab + (size_t)row * 256 + k0 + ((s ^ (row & 7)) << 3), &lA[buf][ci * 8]);
      gload_lds16(Bb + (size_t)row * 256 + k0 + ((s ^ (row & 7)) << 3), &lB[buf][ci * 8]);
    }
  };
  STAGE(0, 0);
  for (int kt = 0; kt < 4; ++kt) {
    if (kt < 3) {
      STAGE((kt + 1) & 1, (kt + 1) * 64);               // prefetch next K-step
      asm volatile("s_waitcnt vmcnt(8)" ::: "memory");  // current step landed
    } else {
      asm volatile("s_waitcnt vmcnt(0)" ::: "memory");
    }
    __builtin_amdgcn_s_barrier();
    const bf16_t* cA = lA[kt & 1];
    const bf16_t* cB = lB[kt & 1];
#pragma unroll
    for (int kk = 0; kk < 2; ++kk) {
      bf16x8 af[4], bfr[4];
#pragma unroll
      for (int mf = 0; mf < 4; ++mf) {
        int r = wm * 64 + mf * 16 + lr;
        int ch = kk * 4 + lk;
        af[mf] = *(const bf16x8*)(cA + r * 64 + ((ch ^ (r & 7)) * 8));
      }
#pragma unroll
      for (int nf = 0; nf < 4; ++nf) {
        int r = wn * 64 + nf * 16 + lr;
        int ch = kk * 4 + lk;
        bfr[nf] = *(const bf16x8*)(cB + r * 64 + ((ch ^ (r & 7)) * 8));
      }
#pragma unroll
      for (int mf = 0; mf < 4; ++mf)
#pragma unroll
        for (int nf = 0; nf < 4; ++nf)
          acc[mf][nf] = __builtin_amdgcn_mfma_f32_16x16x32_bf16(af[mf], bfr[nf],
                                                                acc[mf][nf], 0, 0, 0);
    }
    __builtin_amdgcn_s_barrier();  // reads done before restage overwrites
  }
  int seg = tmi >> 1;
  int rb = (tmi & 1) * 128 + wm * 64;
  int cb = tni * 128 + wn * 64;
  if (seg < 2) {  // Q_t / K_t: transposed bf16 store + bias[r] (+ scale for Q)
    bf16_t* D = (seg ? KTo : QTo) + (size_t)b * (kN * kC);
    const float* bias = seg ? bk : bq;
    float sc = seg ? 1.f : 0.09016844f;  // log2(e)/16 folded into Q
#pragma unroll
    for (int mf = 0; mf < 4; ++mf)
#pragma unroll
      for (int nf = 0; nf < 4; ++nf) {
        int r0 = rb + mf * 16 + lk * 4;
        int c = cb + nf * 16 + lr;
        bf16x4 v;
#pragma unroll
        for (int i = 0; i < 4; ++i) v[i] = (bf16_t)((acc[mf][nf][i] + bias[r0 + i]) * sc);
        *(bf16x4*)(D + (size_t)c * kC + r0) = v;
      }
  } else {  // V: natural bf16 store [c][n] + bias[r]
    bf16_t* D = VVo + (size_t)b * (kC * kN);
#pragma unroll
    for (int mf = 0; mf < 4; ++mf)
#pragma unroll
      for (int nf = 0; nf < 4; ++nf) {
        int r0 = rb + mf * 16 + lk * 4;
        int c = cb + nf * 16 + lr;
#pragma unroll
        for (int i = 0; i < 4; ++i)
          D[(size_t)(r0 + i) * kN + c] = (bf16_t)(acc[mf][nf][i] + bv[r0 + i]);
      }
  }
}

// ---------- out-proj GEMM, double-buffered stage-ahead: f32 store + resid + bias ----------
__global__ __launch_bounds__(256) void out_gemm_k(const bf16_t* __restrict__ A,  // O_t
                                                  const bf16_t* __restrict__ BT, // Wh
                                                  float* __restrict__ Dst,
                                                  const float* __restrict__ bias,
                                                  const float* __restrict__ resid) {
  __shared__ bf16_t lA[2][128 * 64];
  __shared__ bf16_t lB[2][128 * 64];
  int bid = blockIdx.x;
  int b = bid >> 4;
  int rem = bid & 15;
  int tmi = rem >> 1, tni = rem & 1;
  const bf16_t* Ab = A + (size_t)b * (kN * kC) + (size_t)tmi * 128 * 256;
  const bf16_t* Bb = BT + (size_t)tni * 128 * 256;
  int t = threadIdx.x;
  int wid = t >> 6, l = t & 63;
  int wm = wid >> 1, wn = wid & 1;
  int lr = l & 15, lk = l >> 4;
  f32x4 acc[4][4] = {};
  auto STAGE = [&](int buf, int k0) {
#pragma unroll
    for (int i = 0; i < 4; ++i) {
      int ci = i * 256 + t;
      int row = ci >> 3, s = ci & 7;
      gload_lds16(Ab + (size_t)row * 256 + k0 + ((s ^ (row & 7)) << 3), &lA[buf][ci * 8]);
      gload_lds16(Bb + (size_t)row * 256 + k0 + ((s ^ (row & 7)) << 3), &lB[buf][ci * 8]);
    }
  };
  STAGE(0, 0);
  for (int kt = 0; kt < 4; ++kt) {
    if (kt < 3) {
      STAGE((kt + 1) & 1, (kt + 1) * 64);
      asm volatile("s_waitcnt vmcnt(8)" ::: "memory");
    } else {
      asm volatile("s_waitcnt vmcnt(0)" ::: "memory");
    }
    __builtin_amdgcn_s_barrier();
    const bf16_t* cA = lA[kt & 1];
    const bf16_t* cB = lB[kt & 1];
#pragma unroll
    for (int kk = 0; kk < 2; ++kk) {
      bf16x8 af[4], bfr[4];
#pragma unroll
      for (int mf = 0; mf < 4; ++mf) {
        int r = wm * 64 + mf * 16 + lr;
        int ch = kk * 4 + lk;
        af[mf] = *(const bf16x8*)(cA + r * 64 + ((ch ^ (r & 7)) * 8));
      }
#pragma unroll
      for (int nf = 0; nf < 4; ++nf) {
        int r = wn * 64 + nf * 16 + lr;
        int ch = kk * 4 + lk;
        bfr[nf] = *(const bf16x8*)(cB + r * 64 + ((ch ^ (r & 7)) * 8));
      }
#pragma unroll
      for (int mf = 0; mf < 4; ++mf)
#pragma unroll
        for (int nf = 0; nf < 4; ++nf)
          acc[mf][nf] = __builtin_amdgcn_mfma_f32_16x16x32_bf16(af[mf], bfr[nf],
                                                                acc[mf][nf], 0, 0, 0);
    }
    __builtin_amdgcn_s_barrier();
  }
  int rb = tmi * 128 + wm * 64;
  int cb = tni * 128 + wn * 64;
  float* D = Dst + (size_t)b * (kC * kN);
  const float* R = resid + (size_t)b * (kC * kN);
#pragma unroll
  for (int mf = 0; mf < 4; ++mf)
#pragma unroll
    for (int nf = 0; nf < 4; ++nf) {
      int r0 = rb + mf * 16 + lk * 4;  // token n
      int c = cb + nf * 16 + lr;       // channel co
      float4 rv = *(const float4*)(R + (size_t)c * kN + r0);
      float bc = bias[c];
      float4 o2 = make_float4(acc[mf][nf][0] + rv.x + bc, acc[mf][nf][1] + rv.y + bc,
                              acc[mf][nf][2] + rv.z + bc, acc[mf][nf][3] + rv.w + bc);
      *(float4*)(D + (size_t)c * kN + r0) = o2;
    }
}

extern "C" void kernel_launch(void* const* d_in, const int* in_sizes, int n_in,
                              void* d_out, int out_size, void* d_ws, size_t ws_size,
                              hipStream_t stream) {
  (void)in_sizes; (void)n_in; (void)out_size; (void)ws_size;
  const float* x = (const float*)d_in[0];
  const float* gamma = (const float*)d_in[1];
  const float* beta = (const float*)d_in[2];
  const float* wq = (const float*)d_in[3];
  const float* bq = (const float*)d_in[4];
  const float* wk = (const float*)d_in[5];
  const float* bk = (const float*)d_in[6];
  const float* wv = (const float*)d_in[7];
  const float* bv = (const float*)d_in[8];
  const float* wh = (const float*)d_in[9];
  const float* bh = (const float*)d_in[10];
  float* out = (float*)d_out;

  char* ws = (char*)d_ws;
  bf16_t* HN = (bf16_t*)(ws);                // Hn_t [B][N][C]; reused as O_t after fattn
  bf16_t* QT = (bf16_t*)(ws + 16777216);     // Q_t [B][N][C] (pre-scaled)
  bf16_t* KT = (bf16_t*)(ws + 33554432);     // K_t [B][N][C]
  bf16_t* VV = (bf16_t*)(ws + 50331648);     // V   [B][C][N]
  bf16_t* WB = (bf16_t*)(ws + 67108864);     // Wq|Wk|Wv|Wh bf16 (stacked)

  gn_castw_k<<<kB * 32 + 256, 256, 0, stream>>>(x, gamma, beta, HN, wq, wk, wv, wh, WB);
  // Q_t, K_t, V in one dispatch (stacked 768x256 weight)
  qkv_gemm_k<<<kB * 48, 256, 0, stream>>>(WB, HN, QT, KT, VV, bq, bk, bv);
  // fused attention -> O_t in HN
  fattn_k<<<512, 256, 0, stream>>>(QT, KT, VV, HN);
  // out[co][n] = x + (O_t . Wh^T)^T + bh
  out_gemm_k<<<kB * 16, 256, 0, stream>>>(HN, WB + 196608, out, bh, x);
}

// Round 9
// 128.848 us; speedup vs baseline: 1.0427x; 1.0216x over previous
//
#include <hip/hip_runtime.h>

typedef __bf16 bf16_t;
typedef __bf16 bf16x8 __attribute__((ext_vector_type(8)));
typedef __bf16 bf16x4 __attribute__((ext_vector_type(4)));
typedef float f32x4 __attribute__((ext_vector_type(4)));
typedef float f32x16 __attribute__((ext_vector_type(16)));

static constexpr int kC = 256;   // channels
static constexpr int kN = 1024;  // tokens (32x32)
static constexpr int kB = 32;    // batch

__device__ __forceinline__ void gload_lds16(const bf16_t* g, bf16_t* l) {
  __builtin_amdgcn_global_load_lds(
      (const __attribute__((address_space(1))) unsigned int*)g,
      (__attribute__((address_space(3))) unsigned int*)l, 16, 0, 0);
}

__device__ __forceinline__ unsigned cvt_pk_bf16(float a, float b) {
  unsigned r;
  asm("v_cvt_pk_bf16_f32 %0, %1, %2" : "=v"(r) : "v"(a), "v"(b));
  return r;
}

// exchange: a's high 32 lanes <-> b's low 32 lanes (both regs updated)
__device__ __forceinline__ void pl32swap(unsigned& a, unsigned& b) {
  asm("v_permlane32_swap_b32 %0, %1" : "+v"(a), "+v"(b));
}

__device__ __forceinline__ float cross_half_sum(float rs) {
  unsigned a = __builtin_bit_cast(unsigned, rs), b = a;
  pl32swap(a, b);
  return __builtin_bit_cast(float, a) + __builtin_bit_cast(float, b);
}

// ------- fused GroupNorm (+ weight cast blocks): grid = 1024 gn + 256 castw -------
__global__ __launch_bounds__(256) void gn_castw_k(const float* __restrict__ x,
                                                  const float* __restrict__ gamma,
                                                  const float* __restrict__ beta,
                                                  bf16_t* __restrict__ hn,
                                                  const float* __restrict__ wq,
                                                  const float* __restrict__ wk,
                                                  const float* __restrict__ wv,
                                                  const float* __restrict__ wh,
                                                  bf16_t* __restrict__ wb) {
  __shared__ float xs[8 * 1040];  // [c_local][n] pad 1040
  __shared__ float red[8];
  __shared__ float stat[2];
  int t = threadIdx.x;
  if (blockIdx.x >= 1024) {  // weight cast: 256 blocks x 256 thr
    int i = (blockIdx.x - 1024) * 256 + t;
    wb[i] = (bf16_t)wq[i];
    wb[i + 65536] = (bf16_t)wk[i];
    wb[i + 131072] = (bf16_t)wv[i];
    wb[i + 196608] = (bf16_t)wh[i];
    return;
  }
  int bg = blockIdx.x;
  int b = bg >> 5, g = bg & 31;
  const float* base = x + (size_t)bg * 8192;
  float s = 0.f, q = 0.f;
#pragma unroll
  for (int i = 0; i < 8; ++i) {
    float4 v = *(const float4*)(base + i * 1024 + t * 4);
    *(float4*)(xs + i * 1040 + t * 4) = v;
    s += v.x + v.y + v.z + v.w;
    q += v.x * v.x + v.y * v.y + v.z * v.z + v.w * v.w;
  }
#pragma unroll
  for (int o = 32; o; o >>= 1) { s += __shfl_down(s, o); q += __shfl_down(q, o); }
  int w = t >> 6;
  if ((t & 63) == 0) { red[w] = s; red[4 + w] = q; }
  __syncthreads();
  if (t == 0) {
    float S = red[0] + red[1] + red[2] + red[3];
    float Q = red[4] + red[5] + red[6] + red[7];
    float mean = S * (1.f / 8192.f);
    float var = Q * (1.f / 8192.f) - mean * mean;  // biased var matches jnp.var
    stat[0] = mean;
    stat[1] = rsqrtf(var + 1e-5f);
  }
  __syncthreads();
  float mean = stat[0], rstd = stat[1];
  float gmb[8], btb[8];
#pragma unroll
  for (int j = 0; j < 8; ++j) { gmb[j] = gamma[g * 8 + j]; btb[j] = beta[g * 8 + j]; }
  bf16_t* hb = hn + (size_t)b * (kN * kC) + g * 8;
#pragma unroll
  for (int i = 0; i < 4; ++i) {
    int n = i * 256 + t;
    bf16x8 o;
#pragma unroll
    for (int j = 0; j < 8; ++j)
      o[j] = (bf16_t)((xs[j * 1040 + n] - mean) * rstd * gmb[j] + btb[j]);
    *(bf16x8*)(hb + (size_t)n * kC) = o;
  }
}

// ---- fused flash attention v5: all LDS/global addresses hoisted out of the K-loop ----
// 512 blocks x 4 waves (2 qg x 2 h), KVBLK=32, 2 blocks/CU. Fixed-m softmax
// (Q pre-scaled by log2e/16 -> P = exp2(S)); redundant QK per h-pair; PV c-half split.
// QT, KT: [B][N][C] bf16 (Q pre-scaled). VV: [B][C][N]. OT: [B][N][C] bf16.
__global__ __launch_bounds__(256, 2) void fattn_k(const bf16_t* __restrict__ QT,
                                                  const bf16_t* __restrict__ KT,
                                                  const bf16_t* __restrict__ VV,
                                                  bf16_t* __restrict__ OT) {
  __shared__ char smem[65536];  // K[2][32*256] 32K | V[2][256*32] 32K
  bf16_t* lK = (bf16_t*)smem;
  bf16_t* lV = (bf16_t*)(smem + 32768);
  int t = threadIdx.x;
  int wid = t >> 6, lane = t & 63;
  int l31 = lane & 31, hi = lane >> 5;
  int qg = wid & 1, h = wid >> 1;
  int ts = t & 127;
  int bid = blockIdx.x;
  int b = ((bid & 7) << 2) | ((bid >> 3) & 3);  // XCD swizzle (b from low 5 bits)
  int qt = bid >> 5;                            // 0..15
  const bf16_t* Qb = QT + (size_t)b * (kN * kC);
  const bf16_t* Vb = VV + (size_t)b * (kC * kN);
  int q0 = qt * 64 + qg * 32;

  // hoist Q (B-operand): qf[ks] = Qs[q0 + l31][ks*16 + hi*8 .. +7]
  bf16x8 qf[16];
#pragma unroll
  for (int ks = 0; ks < 16; ++ks)
    qf[ks] = *(const bf16x8*)(Qb + (size_t)(q0 + l31) * kC + ks * 16 + hi * 8);

  // ---- loop-invariant LDS read offsets (element units, buf0 base) ----
  unsigned koff[16];
#pragma unroll
  for (int ks = 0; ks < 16; ++ks)
    koff[ks] = l31 * 256 + (((2 * ks + hi) ^ l31) << 3);
  unsigned voff[8];
#pragma unroll
  for (int gs = 0; gs < 2; ++gs)
#pragma unroll
    for (int ct = 0; ct < 4; ++ct) {
      int c = h * 128 + ct * 32 + l31;
      voff[gs * 4 + ct] = c * 32 + (((gs * 2 + hi) ^ ((c >> 1) & 3)) << 3);
    }

  // ---- loop-invariant staging addresses: waves 0-1 stage K, 2-3 stage V ----
  unsigned gsoff[8];
  const bf16_t* gsrc;  // running global base, advances per tile
  bf16_t* ldst0;       // per-lane LDS dest (buf0)
  int gstep;
  if (wid < 2) {
#pragma unroll
    for (int i = 0; i < 8; ++i) {
      int ck = i * 128 + ts;
      int row = ck >> 5, s = ck & 31;
      gsoff[i] = row * 256 + ((s ^ row) << 3);
    }
    gsrc = KT + (size_t)b * (kN * kC);
    ldst0 = lK + ts * 8;
    gstep = 32 * 256;
  } else {
#pragma unroll
    for (int i = 0; i < 8; ++i) {
      int cv = i * 128 + ts;
      int c = cv >> 2, s = cv & 3;
      gsoff[i] = c * 1024 + ((s ^ ((c >> 1) & 3)) << 3);
    }
    gsrc = Vb;
    ldst0 = lV + ts * 8;
    gstep = 32;
  }

  f32x16 acc[4] = {};  // own c-half: col = h*128+ct*32+l31; row q = (r&3)+8*(r>>2)+4*hi
  float lsum = 0.f;

  auto STAGE = [&](int buf) {
    bf16_t* d = ldst0 + buf * 8192;
#pragma unroll
    for (int i = 0; i < 8; ++i)
      gload_lds16(gsrc + gsoff[i], d + i * 1024);
    gsrc += gstep;
  };

  auto COMPUTE = [&](int buf) {
    const bf16_t* bK = lK + buf * 8192;
    const bf16_t* bV = lV + buf * 8192;
    // S^T = K . Q^T : two independent 8-deep chains
    f32x16 sa = {}, sb = {};
    __builtin_amdgcn_s_setprio(1);
#pragma unroll
    for (int ks = 0; ks < 8; ++ks) {
      bf16x8 kf0 = *(const bf16x8*)(bK + koff[ks]);
      sa = __builtin_amdgcn_mfma_f32_32x32x16_bf16(kf0, qf[ks], sa, 0, 0, 0);
      bf16x8 kf1 = *(const bf16x8*)(bK + koff[ks + 8]);
      sb = __builtin_amdgcn_mfma_f32_32x32x16_bf16(kf1, qf[ks + 8], sb, 0, 0, 0);
    }
    __builtin_amdgcn_s_setprio(0);
    // lower P half (rows 0..7) -> pa0 -> PV gs=0 while upper exp runs
    float rs = 0.f;
    float e0, e1, e2, e3, e4, e5, e6, e7;
    e0 = exp2f(sa[0] + sb[0]); e1 = exp2f(sa[1] + sb[1]);
    e2 = exp2f(sa[2] + sb[2]); e3 = exp2f(sa[3] + sb[3]);
    e4 = exp2f(sa[4] + sb[4]); e5 = exp2f(sa[5] + sb[5]);
    e6 = exp2f(sa[6] + sb[6]); e7 = exp2f(sa[7] + sb[7]);
    rs += e0 + e1 + e2 + e3 + e4 + e5 + e6 + e7;
    unsigned A0 = cvt_pk_bf16(e0, e1), A1 = cvt_pk_bf16(e2, e3);
    unsigned B0 = cvt_pk_bf16(e4, e5), B1 = cvt_pk_bf16(e6, e7);
    pl32swap(A0, B0);
    pl32swap(A1, B1);
    uint4 u0 = make_uint4(A0, A1, B0, B1);
    bf16x8 pa0 = __builtin_bit_cast(bf16x8, u0);
    __builtin_amdgcn_s_setprio(1);
#pragma unroll
    for (int ct = 0; ct < 4; ++ct) {
      bf16x8 vf = *(const bf16x8*)(bV + voff[ct]);
      acc[ct] = __builtin_amdgcn_mfma_f32_32x32x16_bf16(pa0, vf, acc[ct], 0, 0, 0);
    }
    __builtin_amdgcn_s_setprio(0);
    // upper P half (rows 8..15): VALU overlaps the in-flight gs0 MFMAs
    e0 = exp2f(sa[8] + sb[8]);   e1 = exp2f(sa[9] + sb[9]);
    e2 = exp2f(sa[10] + sb[10]); e3 = exp2f(sa[11] + sb[11]);
    e4 = exp2f(sa[12] + sb[12]); e5 = exp2f(sa[13] + sb[13]);
    e6 = exp2f(sa[14] + sb[14]); e7 = exp2f(sa[15] + sb[15]);
    rs += e0 + e1 + e2 + e3 + e4 + e5 + e6 + e7;
    unsigned C0 = cvt_pk_bf16(e0, e1), C1 = cvt_pk_bf16(e2, e3);
    unsigned D0 = cvt_pk_bf16(e4, e5), D1 = cvt_pk_bf16(e6, e7);
    pl32swap(C0, D0);
    pl32swap(C1, D1);
    uint4 u1 = make_uint4(C0, C1, D0, D1);
    bf16x8 pa1 = __builtin_bit_cast(bf16x8, u1);
    __builtin_amdgcn_s_setprio(1);
#pragma unroll
    for (int ct = 0; ct < 4; ++ct) {
      bf16x8 vf = *(const bf16x8*)(bV + voff[4 + ct]);
      acc[ct] = __builtin_amdgcn_mfma_f32_32x32x16_bf16(pa1, vf, acc[ct], 0, 0, 0);
    }
    __builtin_amdgcn_s_setprio(0);
    lsum += cross_half_sum(rs);  // full 32-kv row sum for q = l31
  };

  STAGE(0);  // tile 0
  for (int kt = 0; kt < 32; ++kt) {
    if (kt < 31) {
      STAGE((kt + 1) & 1);                              // prefetch tile kt+1
      asm volatile("s_waitcnt vmcnt(8)" ::: "memory");  // tile-kt loads landed
    } else {
      asm volatile("s_waitcnt vmcnt(0)" ::: "memory");
    }
    __builtin_amdgcn_s_barrier();  // tile kt staged for all waves
    COMPUTE(kt & 1);
    __builtin_amdgcn_s_barrier();  // reads done before next-iter restage
  }

  // epilogue: full lsum per q-row (redundant across h); store own c-half
  float inv = 1.f / lsum;
  float invR[16];
#pragma unroll
  for (int r = 0; r < 16; ++r)
    invR[r] = __shfl(inv, (r & 3) + 8 * (r >> 2) + 4 * hi);
  bf16_t* Ob = OT + (size_t)b * (kN * kC);
#pragma unroll
  for (int ct = 0; ct < 4; ++ct)
#pragma unroll
    for (int r = 0; r < 16; ++r) {
      int qr = (r & 3) + 8 * (r >> 2) + 4 * hi;
      Ob[(size_t)(q0 + qr) * kC + h * 128 + ct * 32 + l31] =
          (bf16_t)(acc[ct][r] * invR[r]);
    }
}

// ---------------- merged QKV GEMM, dbuf stage-ahead + hoisted offsets ----------------
// W stacked [768][256]; tmi 0-1 -> Q_t (scaled), 2-3 -> K_t, 4-5 -> V [c][n]
__global__ __launch_bounds__(256) void qkv_gemm_k(const bf16_t* __restrict__ W,
                                                  const bf16_t* __restrict__ HNall,
                                                  bf16_t* __restrict__ QTo,
                                                  bf16_t* __restrict__ KTo,
                                                  bf16_t* __restrict__ VVo,
                                                  const float* __restrict__ bq,
                                                  const float* __restrict__ bk,
                                                  const float* __restrict__ bv) {
  __shared__ bf16_t lA[2][128 * 64];
  __shared__ bf16_t lB[2][128 * 64];
  int bid = blockIdx.x;
  int b = bid / 48;
  int rem = bid - b * 48;
  int tmi = rem >> 3, tni = rem & 7;
  const bf16_t* Ab = W + (size_t)tmi * 128 * 256;
  const bf16_t* Bb = HNall + (size_t)b * (kN * kC) + (size_t)tni * 128 * 256;
  int t = threadIdx.x;
  int wid = t >> 6, l = t & 63;
  int wm = wid >> 1, wn = wid & 1;
  int lr = l & 15, lk = l >> 4;
  // hoisted staging offsets
  unsigned goff[4];
#pragma unroll
  for (int i = 0; i < 4; ++i) {
    int ci = i * 256 + t;
    int row = ci >> 3, s = ci & 7;
    goff[i] = row * 256 + ((s ^ (row & 7)) << 3);
  }
  // hoisted fragment-read offsets
  unsigned aoff[8], boff[8];
#pragma unroll
  for (int kk = 0; kk < 2; ++kk)
#pragma unroll
    for (int f = 0; f < 4; ++f) {
      int ra = wm * 64 + f * 16 + lr;
      int rb2 = wn * 64 + f * 16 + lr;
      int ch = kk * 4 + lk;
      aoff[kk * 4 + f] = ra * 64 + ((ch ^ (ra & 7)) << 3);
      boff[kk * 4 + f] = rb2 * 64 + ((ch ^ (rb2 & 7)) << 3);
    }
  f32x4 acc[4][4] = {};
  auto STAGE = [&](int buf, int k0) {
#pragma unroll
    for (int i = 0; i < 4; ++i) {
      gload_lds16(Ab + k0 + goff[i], &lA[buf][t * 8 + i * 2048]);
      gload_lds16(Bb + k0 + goff[i], &lB[buf][t * 8 + i * 2048]);
    }
  };
  STAGE(0, 0);
  for (int kt = 0; kt < 4; ++kt) {
    if (kt < 3) {
      STAGE((kt + 1) & 1, (kt + 1) * 64);
      asm volatile("s_waitcnt vmcnt(8)" ::: "memory");
    } else {
      asm volatile("s_waitcnt vmcnt(0)" ::: "memory");
    }
    __builtin_amdgcn_s_barrier();
    const bf16_t* cA = lA[kt & 1];
    const bf16_t* cB = lB[kt & 1];
#pragma unroll
    for (int kk = 0; kk < 2; ++kk) {
      bf16x8 af[4], bfr[4];
#pragma unroll
      for (int f = 0; f < 4; ++f) {
        af[f] = *(const bf16x8*)(cA + aoff[kk * 4 + f]);
        bfr[f] = *(const bf16x8*)(cB + boff[kk * 4 + f]);
      }
#pragma unroll
      for (int mf = 0; mf < 4; ++mf)
#pragma unroll
        for (int nf = 0; nf < 4; ++nf)
          acc[mf][nf] = __builtin_amdgcn_mfma_f32_16x16x32_bf16(af[mf], bfr[nf],
                                                                acc[mf][nf], 0, 0, 0);
    }
    __builtin_amdgcn_s_barrier();
  }
  int seg = tmi >> 1;
  int rb = (tmi & 1) * 128 + wm * 64;
  int cb = tni * 128 + wn * 64;
  if (seg < 2) {  // Q_t / K_t: transposed bf16 store + bias[r] (+ scale for Q)
    bf16_t* D = (seg ? KTo : QTo) + (size_t)b * (kN * kC);
    const float* bias = seg ? bk : bq;
    float sc = seg ? 1.f : 0.09016844f;  // log2(e)/16 folded into Q
#pragma unroll
    for (int mf = 0; mf < 4; ++mf)
#pragma unroll
      for (int nf = 0; nf < 4; ++nf) {
        int r0 = rb + mf * 16 + lk * 4;
        int c = cb + nf * 16 + lr;
        bf16x4 v;
#pragma unroll
        for (int i = 0; i < 4; ++i) v[i] = (bf16_t)((acc[mf][nf][i] + bias[r0 + i]) * sc);
        *(bf16x4*)(D + (size_t)c * kC + r0) = v;
      }
  } else {  // V: natural bf16 store [c][n] + bias[r]
    bf16_t* D = VVo + (size_t)b * (kC * kN);
#pragma unroll
    for (int mf = 0; mf < 4; ++mf)
#pragma unroll
      for (int nf = 0; nf < 4; ++nf) {
        int r0 = rb + mf * 16 + lk * 4;
        int c = cb + nf * 16 + lr;
#pragma unroll
        for (int i = 0; i < 4; ++i)
          D[(size_t)(r0 + i) * kN + c] = (bf16_t)(acc[mf][nf][i] + bv[r0 + i]);
      }
  }
}

// ---------- out-proj GEMM, dbuf stage-ahead + hoisted offsets ----------
__global__ __launch_bounds__(256) void out_gemm_k(const bf16_t* __restrict__ A,  // O_t
                                                  const bf16_t* __restrict__ BT, // Wh
                                                  float* __restrict__ Dst,
                                                  const float* __restrict__ bias,
                                                  const float* __restrict__ resid) {
  __shared__ bf16_t lA[2][128 * 64];
  __shared__ bf16_t lB[2][128 * 64];
  int bid = blockIdx.x;
  int b = bid >> 4;
  int rem = bid & 15;
  int tmi = rem >> 1, tni = rem & 1;
  const bf16_t* Ab = A + (size_t)b * (kN * kC) + (size_t)tmi * 128 * 256;
  const bf16_t* Bb = BT + (size_t)tni * 128 * 256;
  int t = threadIdx.x;
  int wid = t >> 6, l = t & 63;
  int wm = wid >> 1, wn = wid & 1;
  int lr = l & 15, lk = l >> 4;
  unsigned goff[4];
#pragma unroll
  for (int i = 0; i < 4; ++i) {
    int ci = i * 256 + t;
    int row = ci >> 3, s = ci & 7;
    goff[i] = row * 256 + ((s ^ (row & 7)) << 3);
  }
  unsigned aoff[8], boff[8];
#pragma unroll
  for (int kk = 0; kk < 2; ++kk)
#pragma unroll
    for (int f = 0; f < 4; ++f) {
      int ra = wm * 64 + f * 16 + lr;
      int rb2 = wn * 64 + f * 16 + lr;
      int ch = kk * 4 + lk;
      aoff[kk * 4 + f] = ra * 64 + ((ch ^ (ra & 7)) << 3);
      boff[kk * 4 + f] = rb2 * 64 + ((ch ^ (rb2 & 7)) << 3);
    }
  f32x4 acc[4][4] = {};
  auto STAGE = [&](int buf, int k0) {
#pragma unroll
    for (int i = 0; i < 4; ++i) {
      gload_lds16(Ab + k0 + goff[i], &lA[buf][t * 8 + i * 2048]);
      gload_lds16(Bb + k0 + goff[i], &lB[buf][t * 8 + i * 2048]);
    }
  };
  STAGE(0, 0);
  for (int kt = 0; kt < 4; ++kt) {
    if (kt < 3) {
      STAGE((kt + 1) & 1, (kt + 1) * 64);
      asm volatile("s_waitcnt vmcnt(8)" ::: "memory");
    } else {
      asm volatile("s_waitcnt vmcnt(0)" ::: "memory");
    }
    __builtin_amdgcn_s_barrier();
    const bf16_t* cA = lA[kt & 1];
    const bf16_t* cB = lB[kt & 1];
#pragma unroll
    for (int kk = 0; kk < 2; ++kk) {
      bf16x8 af[4], bfr[4];
#pragma unroll
      for (int f = 0; f < 4; ++f) {
        af[f] = *(const bf16x8*)(cA + aoff[kk * 4 + f]);
        bfr[f] = *(const bf16x8*)(cB + boff[kk * 4 + f]);
      }
#pragma unroll
      for (int mf = 0; mf < 4; ++mf)
#pragma unroll
        for (int nf = 0; nf < 4; ++nf)
          acc[mf][nf] = __builtin_amdgcn_mfma_f32_16x16x32_bf16(af[mf], bfr[nf],
                                                                acc[mf][nf], 0, 0, 0);
    }
    __builtin_amdgcn_s_barrier();
  }
  int rb = tmi * 128 + wm * 64;
  int cb = tni * 128 + wn * 64;
  float* D = Dst + (size_t)b * (kC * kN);
  const float* R = resid + (size_t)b * (kC * kN);
#pragma unroll
  for (int mf = 0; mf < 4; ++mf)
#pragma unroll
    for (int nf = 0; nf < 4; ++nf) {
      int r0 = rb + mf * 16 + lk * 4;  // token n
      int c = cb + nf * 16 + lr;       // channel co
      float4 rv = *(const float4*)(R + (size_t)c * kN + r0);
      float bc = bias[c];
      float4 o2 = make_float4(acc[mf][nf][0] + rv.x + bc, acc[mf][nf][1] + rv.y + bc,
                              acc[mf][nf][2] + rv.z + bc, acc[mf][nf][3] + rv.w + bc);
      *(float4*)(D + (size_t)c * kN + r0) = o2;
    }
}

extern "C" void kernel_launch(void* const* d_in, const int* in_sizes, int n_in,
                              void* d_out, int out_size, void* d_ws, size_t ws_size,
                              hipStream_t stream) {
  (void)in_sizes; (void)n_in; (void)out_size; (void)ws_size;
  const float* x = (const float*)d_in[0];
  const float* gamma = (const float*)d_in[1];
  const float* beta = (const float*)d_in[2];
  const float* wq = (const float*)d_in[3];
  const float* bq = (const float*)d_in[4];
  const float* wk = (const float*)d_in[5];
  const float* bk = (const float*)d_in[6];
  const float* wv = (const float*)d_in[7];
  const float* bv = (const float*)d_in[8];
  const float* wh = (const float*)d_in[9];
  const float* bh = (const float*)d_in[10];
  float* out = (float*)d_out;

  char* ws = (char*)d_ws;
  bf16_t* HN = (bf16_t*)(ws);                // Hn_t [B][N][C]; reused as O_t after fattn
  bf16_t* QT = (bf16_t*)(ws + 16777216);     // Q_t [B][N][C] (pre-scaled)
  bf16_t* KT = (bf16_t*)(ws + 33554432);     // K_t [B][N][C]
  bf16_t* VV = (bf16_t*)(ws + 50331648);     // V   [B][C][N]
  bf16_t* WB = (bf16_t*)(ws + 67108864);     // Wq|Wk|Wv|Wh bf16 (stacked)

  gn_castw_k<<<kB * 32 + 256, 256, 0, stream>>>(x, gamma, beta, HN, wq, wk, wv, wh, WB);
  // Q_t, K_t, V in one dispatch (stacked 768x256 weight)
  qkv_gemm_k<<<kB * 48, 256, 0, stream>>>(WB, HN, QT, KT, VV, bq, bk, bv);
  // fused attention -> O_t in HN
  fattn_k<<<512, 256, 0, stream>>>(QT, KT, VV, HN);
  // out[co][n] = x + (O_t . Wh^T)^T + bh
  out_gemm_k<<<kB * 16, 256, 0, stream>>>(HN, WB + 196608, out, bh, x);
}